// Round 9
// baseline (164.891 us; speedup 1.0000x reference)
//
#include <hip/hip_runtime.h>
#include <hip/hip_bf16.h>

typedef __hip_bfloat16 bf16;

#define NN 1024   // nodes
#define FD 512    // feature dim (== H)
#define TT 128    // timesteps
#define EE 32768  // edges
#define NBR_CAP 128

// ---- workspace layout (BYTE offsets; ints first) ----
#define OFF_BM   0
#define OFF_DEG  131072
#define OFF_NBR  135168
#define OFF_SAB  659456
#define OFF_SOM  659968
#define OFF_BF   660480
#define BUF_BYTES 1048576  // NN*FD*2 (bf16 intermediates)

// betas = sigmoid(linspace(-6,6,T))*(0.02-1e-4)+1e-4; alphas_bar = cumprod(1-betas)
__global__ void k_sched(float* __restrict__ sab, float* __restrict__ som) {
    if (threadIdx.x == 0) {
        double ab = 1.0;
        for (int k = 0; k < TT; k++) {
            double xk = -6.0 + 12.0 * (double)k / 127.0;
            double beta = 1.0 / (1.0 + exp(-xk)) * (0.02 - 1e-4) + 1e-4;
            ab *= (1.0 - beta);
            sab[k] = (float)sqrt(ab);
            som[k] = (float)sqrt(1.0 - ab);
        }
    }
}

// Fused LayerNorm of x and noise; P0 = LN(x), nz = sign(LN(x))*|sqrt2*LN(noise)|
__global__ __launch_bounds__(256) void k_ln(const float* __restrict__ x,
                                            const float* __restrict__ noise,
                                            bf16* __restrict__ P0,
                                            bf16* __restrict__ nz) {
    int i = blockIdx.x;
    int tA = threadIdx.x, tB = threadIdx.x + 256;
    float x0 = x[i * FD + tA];
    float x1 = x[i * FD + tB];
    float n0 = noise[i * FD + tA];
    float n1 = noise[i * FD + tB];
    float sx = x0 + x1, sxx = x0 * x0 + x1 * x1;
    float sn = n0 + n1, snn = n0 * n0 + n1 * n1;
#pragma unroll
    for (int off = 32; off > 0; off >>= 1) {
        sx  += __shfl_down(sx, off);
        sxx += __shfl_down(sxx, off);
        sn  += __shfl_down(sn, off);
        snn += __shfl_down(snn, off);
    }
    __shared__ float red[4][4];
    int wave = threadIdx.x >> 6, lane = threadIdx.x & 63;
    if (lane == 0) { red[0][wave] = sx; red[1][wave] = sxx; red[2][wave] = sn; red[3][wave] = snn; }
    __syncthreads();
    sx  = red[0][0] + red[0][1] + red[0][2] + red[0][3];
    sxx = red[1][0] + red[1][1] + red[1][2] + red[1][3];
    sn  = red[2][0] + red[2][1] + red[2][2] + red[2][3];
    snn = red[3][0] + red[3][1] + red[3][2] + red[3][3];
    const float inv = 1.0f / FD;
    float mux = sx * inv, varx = sxx * inv - mux * mux;
    float rsx = rsqrtf(varx + 1e-5f);
    float mun = sn * inv, varn = snn * inv - mun * mun;
    float rsn = rsqrtf(varn + 1e-5f);
    const float SQ2 = 1.41421356237309515f;
    float xl0 = (x0 - mux) * rsx, xl1 = (x1 - mux) * rsx;
    float nl0 = fabsf((n0 - mun) * rsn) * SQ2;
    float nl1 = fabsf((n1 - mun) * rsn) * SQ2;
    // sign from post-LN x (faithful: reference reassigns x = LN(x) before sign)
    float s0 = (xl0 > 0.f) ? 1.f : ((xl0 < 0.f) ? -1.f : 0.f);
    float s1 = (xl1 > 0.f) ? 1.f : ((xl1 < 0.f) ? -1.f : 0.f);
    P0[i * FD + tA] = __float2bfloat16(xl0);
    P0[i * FD + tB] = __float2bfloat16(xl1);
    nz[i * FD + tA] = __float2bfloat16(s0 * nl0);
    nz[i * FD + tB] = __float2bfloat16(s1 * nl1);
}

__global__ void k_zero(unsigned int* __restrict__ bm) {
    int idx = blockIdx.x * 256 + threadIdx.x;
    if (idx < NN * 32) bm[idx] = 0u;
}

// adj.at[src,dst].set(1.0) -> bitmap with atomicOr (idempotent: dedups exactly)
__global__ void k_scatter(const int* __restrict__ src, const int* __restrict__ dst,
                          unsigned int* __restrict__ bm) {
    int e = blockIdx.x * 256 + threadIdx.x;
    if (e < EE) {
        int s = src[e], d = dst[e];
        atomicOr(&bm[s * 32 + (d >> 5)], 1u << (d & 31));
    }
}

// Neighbor list + degree from bitmap (deg ~ Binom(32768,1/1024), mean 32; cap 128 >15 sigma)
__global__ void k_compact(const unsigned int* __restrict__ bm, int* __restrict__ deg,
                          int* __restrict__ nbr) {
    int i = blockIdx.x * 256 + threadIdx.x;
    if (i < NN) {
        int cnt = 0;
        for (int w = 0; w < 32; w++) {
            unsigned int m = bm[i * 32 + w];
            while (m) {
                int b = __ffs(m) - 1;
                m &= m - 1;
                if (cnt < NBR_CAP) nbr[i * NBR_CAP + cnt] = w * 32 + b;
                cnt++;
            }
        }
        deg[i] = cnt > NBR_CAP ? NBR_CAP : cnt;
    }
}

// dst = negL @ src, row i: (sum_{j in nbr(i)} src[j,:] - deg_i*src[i,:]) / n
__global__ __launch_bounds__(256) void k_apply(const bf16* __restrict__ src,
                                               bf16* __restrict__ dst,
                                               const int* __restrict__ nbr,
                                               const int* __restrict__ deg) {
    int i = blockIdx.x;
    __shared__ int sn[NBR_CAP];
    int d = deg[i];
    for (int k = threadIdx.x; k < d; k += 256) sn[k] = nbr[i * NBR_CAP + k];
    __syncthreads();
    int fA = threadIdx.x, fB = threadIdx.x + 256;
    float a0 = 0.f, a1 = 0.f;
    for (int k = 0; k < d; k++) {
        const bf16* row = src + sn[k] * FD;
        a0 += __bfloat162float(row[fA]);
        a1 += __bfloat162float(row[fB]);
    }
    float s0 = __bfloat162float(src[i * FD + fA]);
    float s1 = __bfloat162float(src[i * FD + fB]);
    const float inv_n = 1.0f / NN;
    dst[i * FD + fA] = __float2bfloat16((a0 - (float)d * s0) * inv_n);
    dst[i * FD + fB] = __float2bfloat16((a1 - (float)d * s1) * inv_n);
}

// ROUND-9: OUTPUT IS FP32 (reference outputs are jnp.float32; harness contract:
// "bfloat16 -> __hip_bfloat16*, else float*"). Rounds 2-8 wrote bf16 halfwords
// into the fp32 buffer -> packed-garbage comparison -> the stable ~7.25.
// out[0:N*F)    = x_t = sab[t_i]*sel + som[t_i]*nz, sel = negL^{t(t+1)/2}x row i (t>=4 -> 0)
// out[N*F:2N*F) = time_emb_table[t_i]
__global__ __launch_bounds__(256) void k_final(const bf16* __restrict__ P0,
                                               const bf16* __restrict__ P1,
                                               const bf16* __restrict__ P3,
                                               const bf16* __restrict__ P6,
                                               const bf16* __restrict__ nz,
                                               const float* __restrict__ sab,
                                               const float* __restrict__ som,
                                               const int* __restrict__ t,
                                               const float* __restrict__ table,
                                               float* __restrict__ out) {
    int idx = blockIdx.x * 256 + threadIdx.x;
    if (idx < NN * FD) {
        int i = idx >> 9;
        int ti = t[i];
        float sel = 0.f;
        if (ti == 0) sel = __bfloat162float(P0[idx]);
        else if (ti == 1) sel = __bfloat162float(P1[idx]);
        else if (ti == 2) sel = __bfloat162float(P3[idx]);
        else if (ti == 3) sel = __bfloat162float(P6[idx]);
        float nzv = __bfloat162float(nz[idx]);
        out[idx] = sab[ti] * sel + som[ti] * nzv;
    } else if (idx < 2 * NN * FD) {
        int k = idx - NN * FD;
        int i = k >> 9, h = k & 511;
        out[idx] = table[t[i] * FD + h];
    }
}

extern "C" void kernel_launch(void* const* d_in, const int* in_sizes, int n_in,
                              void* d_out, int out_size, void* d_ws, size_t ws_size,
                              hipStream_t stream) {
    const float* x     = (const float*)d_in[0];
    const float* noise = (const float*)d_in[1];
    const float* table = (const float*)d_in[2];
    const int*   src   = (const int*)d_in[3];
    const int*   dst   = (const int*)d_in[4];
    const int*   t     = (const int*)d_in[5];
    float* out = (float*)d_out;

    char* w = (char*)d_ws;
    unsigned int* bm = (unsigned int*)(w + OFF_BM);
    int* deg = (int*)(w + OFF_DEG);
    int* nbr = (int*)(w + OFF_NBR);
    float* sab = (float*)(w + OFF_SAB);
    float* som = (float*)(w + OFF_SOM);
    bf16* P0 = (bf16*)(w + OFF_BF + 0 * BUF_BYTES);
    bf16* nz = (bf16*)(w + OFF_BF + 1 * BUF_BYTES);
    bf16* P1 = (bf16*)(w + OFF_BF + 2 * BUF_BYTES);
    bf16* P3 = (bf16*)(w + OFF_BF + 3 * BUF_BYTES);
    bf16* Ba = (bf16*)(w + OFF_BF + 4 * BUF_BYTES);
    bf16* Bb = (bf16*)(w + OFF_BF + 5 * BUF_BYTES);

    k_sched<<<1, 64, 0, stream>>>(sab, som);
    k_ln<<<NN, 256, 0, stream>>>(x, noise, P0, nz);
    k_zero<<<(NN * 32 + 255) / 256, 256, 0, stream>>>(bm);
    k_scatter<<<(EE + 255) / 256, 256, 0, stream>>>(src, dst, bm);
    k_compact<<<(NN + 255) / 256, 256, 0, stream>>>(bm, deg, nbr);

    // snapshots needed at s = t(t+1)/2: P1 (s=1), P3 (s=3), P6 (s=6)
    k_apply<<<NN, 256, 0, stream>>>(P0, P1, nbr, deg);  // s=1
    k_apply<<<NN, 256, 0, stream>>>(P1, Ba, nbr, deg);  // s=2
    k_apply<<<NN, 256, 0, stream>>>(Ba, P3, nbr, deg);  // s=3
    k_apply<<<NN, 256, 0, stream>>>(P3, Bb, nbr, deg);  // s=4
    k_apply<<<NN, 256, 0, stream>>>(Bb, Ba, nbr, deg);  // s=5
    k_apply<<<NN, 256, 0, stream>>>(Ba, Bb, nbr, deg);  // s=6 -> Bb = P6

    k_final<<<(2 * NN * FD + 255) / 256, 256, 0, stream>>>(P0, P1, P3, Bb, nz, sab, som, t, table, out);
}